// Round 7
// baseline (1333.474 us; speedup 1.0000x reference)
//
#include <hip/hip_runtime.h>
#include <hip/hip_bf16.h>

#define N_ROWS   32768
#define DIM      256
#define DIM4     64
#define K_CODES  1024
#define INV_T    20.0f

#define ROWS_PER_BLK 32
#define CHUNK        32
#define NCHUNK       32     // K_CODES / CHUNK
#define ES_STRIDE    260    // 256+4: 16B-aligned rows, 4-way (not 32-way) on b128

#define Q_OFF    0
#define LOSS_OFF 8388608
#define IDX_OFF  8388609
#define AVG_OFF  8421377

// ---- kernel 1: codebook squared norms, numpy-pairwise-exact fp32 ----
__global__ void vq_norms(const float* __restrict__ emb, float* __restrict__ ne) {
    int k = blockIdx.x * blockDim.x + threadIdx.x;
    if (k >= K_CODES) return;
    const float* row = emb + (size_t)k * DIM;
    float blk[2];
    #pragma unroll
    for (int b = 0; b < 2; ++b) {
        const float* x = row + b * 128;
        float r[8];
        #pragma unroll
        for (int j = 0; j < 8; ++j) r[j] = __fmul_rn(x[j], x[j]);
        for (int i = 8; i < 128; i += 8) {
            #pragma unroll
            for (int j = 0; j < 8; ++j)
                r[j] = __fadd_rn(r[j], __fmul_rn(x[i + j], x[i + j]));
        }
        float t01 = __fadd_rn(r[0], r[1]);
        float t23 = __fadd_rn(r[2], r[3]);
        float t45 = __fadd_rn(r[4], r[5]);
        float t67 = __fadd_rn(r[6], r[7]);
        blk[b] = __fadd_rn(__fadd_rn(t01, t23), __fadd_rn(t45, t67));
    }
    ne[k] = __fadd_rn(blk[0], blk[1]);
}

// ---- kernel 2: zero the accumulated outputs ----
__global__ void vq_init(float* __restrict__ out) {
    int i = blockIdx.x * blockDim.x + threadIdx.x;
    if (i == 0) out[LOSS_OFF] = 0.f;
    if (i < K_CODES) out[AVG_OFF + i] = 0.f;
}

// ---- kernel 3: fused distances/argmin/softmax/gather/losses ----
// Pipe-split operand feed: e staged coalesced into LDS (1 b128/K-step),
// z read from global as group-broadcast loads (VMEM pipe, L1/L2-resident
// 32KB tile). T14 staging split: next chunk's loads issued before compute.
__global__ __launch_bounds__(256) void vq_main(
    const float4* __restrict__ z4,
    const float4* __restrict__ emb4,
    const float* __restrict__ ne,
    float* __restrict__ out)
{
    __shared__ float es[CHUNK * ES_STRIDE];          // 33.3 KB
    __shared__ float avg_lds[K_CODES];               // 4 KB
    __shared__ float nzs[ROWS_PER_BLK];
    __shared__ int   bestIdx[ROWS_PER_BLK];
    __shared__ float redbuf[4];

    const int t  = threadIdx.x;
    const int n0 = blockIdx.x * ROWS_PER_BLK;
    const int c  = t & 31;   // code lane within chunk
    const int g  = t >> 5;   // row group 0..7 -> rows g*4 .. g*4+3

    #pragma unroll
    for (int i = 0; i < 4; ++i) avg_lds[i * 256 + t] = 0.f;

    // ---- ||z||^2 per row, numpy-pairwise-exact (16 lanes/row), from global ----
    // xor-tree 1,2,4 reproduces ((r0+r1)+(r2+r3))+((r4+r5)+(r6+r7)); xor 8 = B0+B1.
    {
        const int lane = t & 63;
        const int wv   = t >> 6;
        const int j8   = lane & 7;
        const int blk  = (lane >> 3) & 1;
        const int rsub = lane >> 4;
        const float* zf = reinterpret_cast<const float*>(z4);
        #pragma unroll
        for (int p = 0; p < 2; ++p) {
            int row = p * 16 + wv * 4 + rsub;
            const float* x = zf + (size_t)(n0 + row) * DIM + blk * 128;
            float v0 = x[j8];
            float s = __fmul_rn(v0, v0);
            #pragma unroll
            for (int b = 1; b < 16; ++b) {
                float v = x[j8 + 8 * b];
                s = __fadd_rn(s, __fmul_rn(v, v));
            }
            s = __fadd_rn(s, __shfl_xor(s, 1));
            s = __fadd_rn(s, __shfl_xor(s, 2));
            s = __fadd_rn(s, __shfl_xor(s, 4));
            s = __fadd_rn(s, __shfl_xor(s, 8));   // B0 + B1
            if ((lane & 15) == 0) nzs[row] = s;
        }
    }

    // ---- stage chunk 0 ----
    float4 st[8];
    #pragma unroll
    for (int i = 0; i < 8; ++i) {
        int f = i * 256 + t;
        st[i] = emb4[(size_t)(f >> 6) * DIM4 + (f & 63)];
    }
    #pragma unroll
    for (int i = 0; i < 8; ++i) {
        int f = i * 256 + t;
        *reinterpret_cast<float4*>(&es[(f >> 6) * ES_STRIDE + (f & 63) * 4]) = st[i];
    }
    __syncthreads();   // es chunk0 + nzs visible

    // z row pointers (global; 32 lanes of a group share addresses -> broadcast)
    const float4* zr0 = z4 + (size_t)(n0 + g * 4 + 0) * DIM4;
    const float4* zr1 = z4 + (size_t)(n0 + g * 4 + 1) * DIM4;
    const float4* zr2 = z4 + (size_t)(n0 + g * 4 + 2) * DIM4;
    const float4* zr3 = z4 + (size_t)(n0 + g * 4 + 3) * DIM4;

    float acc[NCHUNK][4];   // dot(z_row, e_code); fully unrolled => registers

    #pragma unroll
    for (int jc = 0; jc < NCHUNK; ++jc) {
        // T14: issue next chunk's global loads before compute (latency hides)
        if (jc + 1 < NCHUNK) {
            #pragma unroll
            for (int i = 0; i < 8; ++i) {
                int f = i * 256 + t;
                st[i] = emb4[(size_t)((jc + 1) * CHUNK + (f >> 6)) * DIM4 + (f & 63)];
            }
        }

        const float4* erow = reinterpret_cast<const float4*>(&es[c * ES_STRIDE]);
        // single sequential FMA chain per (row,code), ascending d — bit-exact
        float a0 = 0.f, a1 = 0.f, a2 = 0.f, a3 = 0.f;
        #pragma unroll 4
        for (int d4 = 0; d4 < DIM4; ++d4) {
            float4 e4 = erow[d4];
            float4 v0 = zr0[d4];
            float4 v1 = zr1[d4];
            float4 v2 = zr2[d4];
            float4 v3 = zr3[d4];
            a0 = __builtin_fmaf(v0.x, e4.x, a0);
            a0 = __builtin_fmaf(v0.y, e4.y, a0);
            a0 = __builtin_fmaf(v0.z, e4.z, a0);
            a0 = __builtin_fmaf(v0.w, e4.w, a0);
            a1 = __builtin_fmaf(v1.x, e4.x, a1);
            a1 = __builtin_fmaf(v1.y, e4.y, a1);
            a1 = __builtin_fmaf(v1.z, e4.z, a1);
            a1 = __builtin_fmaf(v1.w, e4.w, a1);
            a2 = __builtin_fmaf(v2.x, e4.x, a2);
            a2 = __builtin_fmaf(v2.y, e4.y, a2);
            a2 = __builtin_fmaf(v2.z, e4.z, a2);
            a2 = __builtin_fmaf(v2.w, e4.w, a2);
            a3 = __builtin_fmaf(v3.x, e4.x, a3);
            a3 = __builtin_fmaf(v3.y, e4.y, a3);
            a3 = __builtin_fmaf(v3.z, e4.z, a3);
            a3 = __builtin_fmaf(v3.w, e4.w, a3);
        }
        acc[jc][0] = a0; acc[jc][1] = a1; acc[jc][2] = a2; acc[jc][3] = a3;

        __syncthreads();   // all waves done reading es
        if (jc + 1 < NCHUNK) {
            #pragma unroll
            for (int i = 0; i < 8; ++i) {
                int f = i * 256 + t;
                *reinterpret_cast<float4*>(&es[(f >> 6) * ES_STRIDE + (f & 63) * 4]) = st[i];
            }
            __syncthreads();   // new es visible
        }
    }

    // ---- distances exactly as np: d = RN( RN(nz + ne_k) - 2*dot ) ----
    float nzv[4];
    #pragma unroll
    for (int r = 0; r < 4; ++r) nzv[r] = nzs[g * 4 + r];

    #pragma unroll
    for (int jc = 0; jc < NCHUNK; ++jc) {
        float nv = ne[jc * CHUNK + c];
        #pragma unroll
        for (int r = 0; r < 4; ++r) {
            float S = __fadd_rn(nzv[r], nv);
            acc[jc][r] = __fsub_rn(S, 2.f * acc[jc][r]);   // 2*dot exact; single RN sub
        }
    }

    float pa[NCHUNK];
    #pragma unroll
    for (int jc = 0; jc < NCHUNK; ++jc) pa[jc] = 0.f;

    #pragma unroll
    for (int r = 0; r < 4; ++r) {
        // lane-local argmin (ascending code order; strict < keeps first index)
        float m = acc[0][r];
        int   bi = c;
        #pragma unroll
        for (int jc = 1; jc < NCHUNK; ++jc) {
            float v = acc[jc][r];
            if (v < m) { m = v; bi = jc * CHUNK + c; }
        }
        // 32-lane reduce; tie -> smaller index (np argmin first-occurrence)
        #pragma unroll
        for (int off = 16; off >= 1; off >>= 1) {
            float om = __shfl_xor(m, off);
            int   oi = __shfl_xor(bi, off);
            if (om < m || (om == m && oi < bi)) { m = om; bi = oi; }
        }
        // softmax(-d/T): p = exp((dmin - d)*INV_T) / sum
        float s = 0.f;
        #pragma unroll
        for (int jc = 0; jc < NCHUNK; ++jc) s += __expf((m - acc[jc][r]) * INV_T);
        #pragma unroll
        for (int off = 16; off >= 1; off >>= 1) s += __shfl_xor(s, off);
        float inv_s = 1.f / s;
        #pragma unroll
        for (int jc = 0; jc < NCHUNK; ++jc)
            pa[jc] += __expf((m - acc[jc][r]) * INV_T) * inv_s;
        if (c == 0) bestIdx[g * 4 + r] = bi;
    }

    #pragma unroll
    for (int jc = 0; jc < NCHUNK; ++jc)
        atomicAdd(&avg_lds[jc * CHUNK + c], pa[jc]);

    __syncthreads();

    #pragma unroll
    for (int i = 0; i < 4; ++i) {
        int k = i * 256 + t;
        atomicAdd(&out[AVG_OFF + k], avg_lds[k] * (1.0f / (float)N_ROWS));
    }

    if (t < ROWS_PER_BLK) out[IDX_OFF + n0 + t] = (float)bestIdx[t];

    // quantized output (gather emb[idx]) + fused vq loss (z re-read from L2)
    float lpart = 0.f;
    #pragma unroll
    for (int i = 0; i < 8; ++i) {
        int f = i * 256 + t;
        int r = f >> 6, d4 = f & 63;
        int bi = bestIdx[r];
        float4 q = emb4[(size_t)bi * DIM4 + d4];
        reinterpret_cast<float4*>(out)[(size_t)(n0 + r) * DIM4 + d4] = q;
        float4 zz = z4[(size_t)(n0 + r) * DIM4 + d4];
        float dx = q.x - zz.x, dy = q.y - zz.y, dz = q.z - zz.z, dw = q.w - zz.w;
        lpart += dx * dx + dy * dy + dz * dz + dw * dw;
    }
    #pragma unroll
    for (int off = 32; off >= 1; off >>= 1) lpart += __shfl_xor(lpart, off);
    int wid = t >> 6;
    if ((t & 63) == 0) redbuf[wid] = lpart;
    __syncthreads();
    if (t == 0) {
        float tot = redbuf[0] + redbuf[1] + redbuf[2] + redbuf[3];
        atomicAdd(&out[LOSS_OFF], tot * (1.25f / (float)(N_ROWS * DIM)));
    }
}

extern "C" void kernel_launch(void* const* d_in, const int* in_sizes, int n_in,
                              void* d_out, int out_size, void* d_ws, size_t ws_size,
                              hipStream_t stream) {
    const float* z   = (const float*)d_in[0];
    const float* emb = (const float*)d_in[1];
    float* out = (float*)d_out;
    float* ne  = (float*)d_ws;   // 1024 floats of scratch

    vq_norms<<<dim3(4), dim3(256), 0, stream>>>(emb, ne);
    vq_init<<<dim3(4), dim3(256), 0, stream>>>(out);
    vq_main<<<dim3(N_ROWS / ROWS_PER_BLK), dim3(256), 0, stream>>>(
        (const float4*)z, (const float4*)emb, ne, out);
}

// Round 9
// 328.180 us; speedup vs baseline: 4.0632x; 4.0632x over previous
//
#include <hip/hip_runtime.h>
#include <hip/hip_bf16.h>

#define N_ROWS   32768
#define DIM      256
#define DIM4     64
#define K_CODES  1024
#define INV_T    20.0f
#define SCREEN_W 4e-4f

#define LOSS_OFF 8388608
#define IDX_OFF  8388609
#define AVG_OFF  8421377

typedef float  f32x4  __attribute__((ext_vector_type(4)));
typedef short  short8 __attribute__((ext_vector_type(8)));
typedef unsigned long long u64;

static __device__ __forceinline__ unsigned short f2bf(float x) {
    union { __hip_bfloat16 b; unsigned short u; } v;
    v.b = __float2bfloat16(x);
    return v.u;
}
static __device__ __forceinline__ float bf2f(unsigned short h) {
    union { unsigned int u; float f; } v;
    v.u = ((unsigned int)h) << 16;
    return v.f;
}

// ---- kernel 1: codebook squared norms, numpy-pairwise-exact fp32 (validated) ----
__global__ void vq_norms(const float* __restrict__ emb, float* __restrict__ ne) {
    int k = blockIdx.x * blockDim.x + threadIdx.x;
    if (k >= K_CODES) return;
    const float* row = emb + (size_t)k * DIM;
    float blk[2];
    #pragma unroll
    for (int b = 0; b < 2; ++b) {
        const float* x = row + b * 128;
        float r[8];
        #pragma unroll
        for (int j = 0; j < 8; ++j) r[j] = __fmul_rn(x[j], x[j]);
        for (int i = 8; i < 128; i += 8) {
            #pragma unroll
            for (int j = 0; j < 8; ++j)
                r[j] = __fadd_rn(r[j], __fmul_rn(x[i + j], x[i + j]));
        }
        float t01 = __fadd_rn(r[0], r[1]);
        float t23 = __fadd_rn(r[2], r[3]);
        float t45 = __fadd_rn(r[4], r[5]);
        float t67 = __fadd_rn(r[6], r[7]);
        blk[b] = __fadd_rn(__fadd_rn(t01, t23), __fadd_rn(t45, t67));
    }
    ne[k] = __fadd_rn(blk[0], blk[1]);
}

// ---- kernel 2: zero the accumulated outputs ----
__global__ void vq_init(float* __restrict__ out) {
    int i = blockIdx.x * blockDim.x + threadIdx.x;
    if (i == 0) out[LOSS_OFF] = 0.f;
    if (i < K_CODES) out[AVG_OFF + i] = 0.f;
}

// ---- kernel 3: MFMA screening + np-exact candidate argmin ----
// Block: 32 rows x 1024 codes, 256 threads = 4 waves.
// Wave w: row-tile rt=w&1 (16 rows), code-half ch=w>>1 (512 codes).
// d~ = nz + ne - 2*(zh*eh + zh*el + zl*eh)  via mfma_f32_16x16x32_bf16.
// Exact pass (validated np-bit-exact chain) only for screened candidates.
__global__ __launch_bounds__(256) void vq_main(
    const float4* __restrict__ z4,
    const float4* __restrict__ emb4,
    const float* __restrict__ ne,
    float* __restrict__ out)
{
    __shared__ __align__(16) char uni[32768];          // zs fp32  ->  es bf16 (eh/el)
    __shared__ __align__(16) unsigned short zhs[8192]; // zh [32][256] (swizzled cols)
    __shared__ __align__(16) unsigned short zls[8192]; // zl
    __shared__ float avg_lds[K_CODES];
    __shared__ float nzs[32];
    __shared__ float rowmin2[32][2];
    __shared__ float rowsum2[32][2];
    __shared__ u64   rowwin[32];
    __shared__ unsigned int list[512];
    __shared__ int   listCount;
    __shared__ float redbuf[4];

    const int t    = threadIdx.x;
    const int n0   = blockIdx.x * 32;
    const int lane = t & 63;
    const int w    = t >> 6;
    const int rt   = w & 1;    // row tile
    const int ch   = w >> 1;   // code half

    #pragma unroll
    for (int i = 0; i < 4; ++i) avg_lds[i * 256 + t] = 0.f;
    if (t < 32) rowwin[t] = ~0ull;
    if (t == 0) listCount = 0;

    // ---- stage z fp32 tile into uni (row-major [32][256]) ----
    float* zs = reinterpret_cast<float*>(uni);
    #pragma unroll
    for (int i = 0; i < 8; ++i) {
        int f = i * 256 + t;
        reinterpret_cast<float4*>(zs)[f] = z4[(size_t)n0 * DIM4 + f];
    }
    __syncthreads();

    // ---- ||z||^2, numpy-pairwise-exact (validated verbatim) ----
    {
        const int j8   = lane & 7;
        const int blk  = (lane >> 3) & 1;
        const int rsub = lane >> 4;
        #pragma unroll
        for (int p = 0; p < 2; ++p) {
            int row = p * 16 + w * 4 + rsub;
            const float* x = zs + row * 256 + blk * 128;
            float v0 = x[j8];
            float s = __fmul_rn(v0, v0);
            #pragma unroll
            for (int b = 1; b < 16; ++b) {
                float v = x[j8 + 8 * b];
                s = __fadd_rn(s, __fmul_rn(v, v));
            }
            s = __fadd_rn(s, __shfl_xor(s, 1));
            s = __fadd_rn(s, __shfl_xor(s, 2));
            s = __fadd_rn(s, __shfl_xor(s, 4));
            s = __fadd_rn(s, __shfl_xor(s, 8));
            if ((lane & 15) == 0) nzs[row] = s;
        }
    }

    // ---- z -> bf16 hi/lo into zhs/zls, col-bytes XOR-swizzled by (row&7)<<4 ----
    #pragma unroll
    for (int i = 0; i < 32; ++i) {
        int f = i * 256 + t;            // [0, 8192)
        int row = f >> 8, d = f & 255;
        float zv = zs[f];
        unsigned short h = f2bf(zv);
        unsigned short l = f2bf(zv - bf2f(h));
        int colb = (d * 2) ^ ((row & 7) << 4);
        *reinterpret_cast<unsigned short*>(reinterpret_cast<char*>(zhs) + row * 512 + colb) = h;
        *reinterpret_cast<unsigned short*>(reinterpret_cast<char*>(zls) + row * 512 + colb) = l;
    }
    __syncthreads();   // zhs/zls ready; zs region now free for es

    // ---- A-fragments: zh preloaded (8 ksteps), zl streamed ----
    const int arow = rt * 16 + (lane & 15);
    const int hi16 = (lane >> 4) * 16;
    const int swzr = (arow & 7) << 4;
    const char* zhb = reinterpret_cast<const char*>(zhs) + arow * 512;
    const char* zlb = reinterpret_cast<const char*>(zls) + arow * 512;
    short8 azh[8];
    #pragma unroll
    for (int k = 0; k < 8; ++k)
        azh[k] = *reinterpret_cast<const short8*>(zhb + ((k * 64 + hi16) ^ swzr));

    f32x4 acc[32];
    #pragma unroll
    for (int i = 0; i < 32; ++i) acc[i] = (f32x4){0.f, 0.f, 0.f, 0.f};

    // b-frag addressing (per-lane constants)
    const int bc    = lane & 15;            // code within 16-tile
    const int swzc  = (bc & 7) << 4;
    const char* ebase = uni + ch * 16384 + bc * 512;

    // ---- chunk loop: 32 iters x 16 codes/half staged as bf16 hi/lo ----
    #pragma unroll
    for (int it = 0; it < 32; ++it) {
        // stage 32 codes (16 per half): fp32 global -> bf16 hi/lo, swizzled
        #pragma unroll
        for (int i = 0; i < 8; ++i) {
            int f = i * 256 + t;              // [0, 2048)
            int cr = f >> 6, d4 = f & 63;
            int half = cr >> 4, c = cr & 15;
            int gcode = half * 512 + it * 16 + c;
            float4 e4 = emb4[(size_t)gcode * DIM4 + d4];
            ushort4 h4, l4;
            h4.x = f2bf(e4.x); l4.x = f2bf(e4.x - bf2f(h4.x));
            h4.y = f2bf(e4.y); l4.y = f2bf(e4.y - bf2f(h4.y));
            h4.z = f2bf(e4.z); l4.z = f2bf(e4.z - bf2f(h4.z));
            h4.w = f2bf(e4.w); l4.w = f2bf(e4.w - bf2f(h4.w));
            char* base = uni + half * 16384 + c * 512;
            int kbs = (d4 * 8) ^ ((c & 7) << 4);
            *reinterpret_cast<ushort4*>(base + kbs) = h4;
            *reinterpret_cast<ushort4*>(base + 8192 + kbs) = l4;
        }
        __syncthreads();

        #pragma unroll
        for (int k = 0; k < 8; ++k) {
            int off = (k * 64 + hi16) ^ swzc;
            short8 ebh = *reinterpret_cast<const short8*>(ebase + off);
            short8 ebl = *reinterpret_cast<const short8*>(ebase + 8192 + off);
            short8 azl = *reinterpret_cast<const short8*>(zlb + ((k * 64 + hi16) ^ swzr));
            acc[it] = __builtin_amdgcn_mfma_f32_16x16x32_bf16(azh[k], ebh, acc[it], 0, 0, 0);
            acc[it] = __builtin_amdgcn_mfma_f32_16x16x32_bf16(azh[k], ebl, acc[it], 0, 0, 0);
            acc[it] = __builtin_amdgcn_mfma_f32_16x16x32_bf16(azl,    ebh, acc[it], 0, 0, 0);
        }
        __syncthreads();
    }

    // C/D layout (m89-verified): col = lane&15, row = (lane>>4)*4 + reg
    const int lrow0 = rt * 16 + (lane >> 4) * 4;   // rows lrow0..lrow0+3 (block-local)
    float nzv[4];
    #pragma unroll
    for (int r = 0; r < 4; ++r) nzv[r] = nzs[lrow0 + r];

    // ---- d~ = (nz + ne) - 2*dot (screening precision) ----
    #pragma unroll
    for (int it = 0; it < 32; ++it) {
        int code = ch * 512 + it * 16 + (lane & 15);
        float nev = ne[code];
        #pragma unroll
        for (int r = 0; r < 4; ++r)
            acc[it][r] = (nzv[r] + nev) - 2.f * acc[it][r];
    }

    // ---- per-row min of d~ ----
    float mn[4] = {3.4e38f, 3.4e38f, 3.4e38f, 3.4e38f};
    #pragma unroll
    for (int it = 0; it < 32; ++it) {
        #pragma unroll
        for (int r = 0; r < 4; ++r) mn[r] = fminf(mn[r], acc[it][r]);
    }
    #pragma unroll
    for (int r = 0; r < 4; ++r) {
        mn[r] = fminf(mn[r], __shfl_xor(mn[r], 1));
        mn[r] = fminf(mn[r], __shfl_xor(mn[r], 2));
        mn[r] = fminf(mn[r], __shfl_xor(mn[r], 4));
        mn[r] = fminf(mn[r], __shfl_xor(mn[r], 8));
    }
    if ((lane & 15) == 0) {
        #pragma unroll
        for (int r = 0; r < 4; ++r) rowmin2[lrow0 + r][ch] = mn[r];
    }
    __syncthreads();
    float rmn[4];
    #pragma unroll
    for (int r = 0; r < 4; ++r)
        rmn[r] = fminf(rowmin2[lrow0 + r][0], rowmin2[lrow0 + r][1]);

    // ---- candidate screen (push to LDS list) ----
    #pragma unroll
    for (int it = 0; it < 32; ++it) {
        int code = ch * 512 + it * 16 + (lane & 15);
        #pragma unroll
        for (int r = 0; r < 4; ++r) {
            if (acc[it][r] <= rmn[r] + SCREEN_W) {
                int idx = atomicAdd(&listCount, 1);
                if (idx < 512) list[idx] = ((unsigned int)(lrow0 + r) << 10) | (unsigned int)code;
            }
        }
    }

    // ---- softmax numerators (overwrite acc) + row sums ----
    float sm[4] = {0.f, 0.f, 0.f, 0.f};
    #pragma unroll
    for (int it = 0; it < 32; ++it) {
        #pragma unroll
        for (int r = 0; r < 4; ++r) {
            float u = __expf((rmn[r] - acc[it][r]) * INV_T);
            acc[it][r] = u;
            sm[r] += u;
        }
    }
    #pragma unroll
    for (int r = 0; r < 4; ++r) {
        sm[r] += __shfl_xor(sm[r], 1);
        sm[r] += __shfl_xor(sm[r], 2);
        sm[r] += __shfl_xor(sm[r], 4);
        sm[r] += __shfl_xor(sm[r], 8);
    }
    if ((lane & 15) == 0) {
        #pragma unroll
        for (int r = 0; r < 4; ++r) rowsum2[lrow0 + r][ch] = sm[r];
    }
    __syncthreads();   // rowsums + candidate list complete

    float inv[4];
    #pragma unroll
    for (int r = 0; r < 4; ++r)
        inv[r] = 1.f / (rowsum2[lrow0 + r][0] + rowsum2[lrow0 + r][1]);

    // ---- per-code soft-prob partials -> avg_lds ----
    #pragma unroll
    for (int it = 0; it < 32; ++it) {
        float pit = acc[it][0] * inv[0] + acc[it][1] * inv[1]
                  + acc[it][2] * inv[2] + acc[it][3] * inv[3];
        pit += __shfl_xor(pit, 16);
        pit += __shfl_xor(pit, 32);
        if (lane < 16)
            atomicAdd(&avg_lds[ch * 512 + it * 16 + lane], pit);
    }

    // ---- np-exact recompute for candidates (validated chain, verbatim) ----
    {
        int cnt = listCount; if (cnt > 512) cnt = 512;
        for (int i = t; i < cnt; i += 256) {
            unsigned int p = list[i];
            int lrow = (int)(p >> 10);
            int code = (int)(p & 1023u);
            const float4* zr = z4 + (size_t)(n0 + lrow) * DIM4;
            const float4* er = emb4 + (size_t)code * DIM4;
            float a0 = 0.f;
            for (int d4 = 0; d4 < DIM4; ++d4) {
                float4 v = zr[d4];
                float4 e = er[d4];
                a0 = __builtin_fmaf(v.x, e.x, a0);
                a0 = __builtin_fmaf(v.y, e.y, a0);
                a0 = __builtin_fmaf(v.z, e.z, a0);
                a0 = __builtin_fmaf(v.w, e.w, a0);
            }
            float S = __fadd_rn(nzs[lrow], ne[code]);
            float d = __fsub_rn(S, 2.f * a0);
            u64 key = ((u64)__float_as_uint(d) << 32) | (u64)(unsigned int)code;
            atomicMin(&rowwin[lrow], key);
        }
    }
    __syncthreads();

    // ---- outputs ----
    #pragma unroll
    for (int i = 0; i < 4; ++i) {
        int k = i * 256 + t;
        atomicAdd(&out[AVG_OFF + k], avg_lds[k] * (1.0f / (float)N_ROWS));
    }
    if (t < 32)
        out[IDX_OFF + n0 + t] = (float)(unsigned int)(rowwin[t] & 0xFFFFFFFFull);

    // quantized output (gather emb[idx]) + fused vq loss (z from global/L2)
    float lpart = 0.f;
    #pragma unroll
    for (int i = 0; i < 8; ++i) {
        int f = i * 256 + t;
        int r = f >> 6, d4 = f & 63;
        int bi = (int)(unsigned int)(rowwin[r] & 0xFFFFFFFFull);
        float4 q = emb4[(size_t)bi * DIM4 + d4];
        reinterpret_cast<float4*>(out)[(size_t)(n0 + r) * DIM4 + d4] = q;
        float4 zz = z4[(size_t)(n0 + r) * DIM4 + d4];
        float dx = q.x - zz.x, dy = q.y - zz.y, dz = q.z - zz.z, dw = q.w - zz.w;
        lpart += dx * dx + dy * dy + dz * dz + dw * dw;
    }
    #pragma unroll
    for (int off = 32; off >= 1; off >>= 1) lpart += __shfl_xor(lpart, off);
    if ((t & 63) == 0) redbuf[t >> 6] = lpart;
    __syncthreads();
    if (t == 0) {
        float tot = redbuf[0] + redbuf[1] + redbuf[2] + redbuf[3];
        atomicAdd(&out[LOSS_OFF], tot * (1.25f / (float)(N_ROWS * DIM)));
    }
}

extern "C" void kernel_launch(void* const* d_in, const int* in_sizes, int n_in,
                              void* d_out, int out_size, void* d_ws, size_t ws_size,
                              hipStream_t stream) {
    const float* z   = (const float*)d_in[0];
    const float* emb = (const float*)d_in[1];
    float* out = (float*)d_out;
    float* ne  = (float*)d_ws;   // 1024 floats of scratch

    vq_norms<<<dim3(4), dim3(256), 0, stream>>>(emb, ne);
    vq_init<<<dim3(4), dim3(256), 0, stream>>>(out);
    vq_main<<<dim3(N_ROWS / 32), dim3(256), 0, stream>>>(
        (const float4*)z, (const float4*)emb, ne, out);
}

// Round 10
// 317.746 us; speedup vs baseline: 4.1967x; 1.0328x over previous
//
#include <hip/hip_runtime.h>
#include <hip/hip_bf16.h>

#define N_ROWS   32768
#define DIM      256
#define DIM4     64
#define K_CODES  1024
#define INV_T    20.0f
#define SCREEN_W 5e-4f

#define LOSS_OFF 8388608
#define IDX_OFF  8388609
#define AVG_OFF  8421377

typedef float  f32x4   __attribute__((ext_vector_type(4)));
typedef short  short8  __attribute__((ext_vector_type(8)));
typedef unsigned short ushort8 __attribute__((ext_vector_type(8)));
typedef unsigned long long u64;

static __device__ __forceinline__ unsigned short f2bf(float x) {
    union { __hip_bfloat16 b; unsigned short u; } v;
    v.b = __float2bfloat16(x);
    return v.u;
}

// ---- kernel 1: codebook squared norms, numpy-pairwise-exact fp32 (validated) ----
__global__ void vq_norms(const float* __restrict__ emb, float* __restrict__ ne) {
    int k = blockIdx.x * blockDim.x + threadIdx.x;
    if (k >= K_CODES) return;
    const float* row = emb + (size_t)k * DIM;
    float blk[2];
    #pragma unroll
    for (int b = 0; b < 2; ++b) {
        const float* x = row + b * 128;
        float r[8];
        #pragma unroll
        for (int j = 0; j < 8; ++j) r[j] = __fmul_rn(x[j], x[j]);
        for (int i = 8; i < 128; i += 8) {
            #pragma unroll
            for (int j = 0; j < 8; ++j)
                r[j] = __fadd_rn(r[j], __fmul_rn(x[i + j], x[i + j]));
        }
        float t01 = __fadd_rn(r[0], r[1]);
        float t23 = __fadd_rn(r[2], r[3]);
        float t45 = __fadd_rn(r[4], r[5]);
        float t67 = __fadd_rn(r[6], r[7]);
        blk[b] = __fadd_rn(__fadd_rn(t01, t23), __fadd_rn(t45, t67));
    }
    ne[k] = __fadd_rn(blk[0], blk[1]);
}

// ---- kernel 2: zero the accumulated outputs ----
__global__ void vq_init(float* __restrict__ out) {
    int i = blockIdx.x * blockDim.x + threadIdx.x;
    if (i == 0) out[LOSS_OFF] = 0.f;
    if (i < K_CODES) out[AVG_OFF + i] = 0.f;
}

// ---- kernel 3: MFMA screening (zh*eh only) + np-exact candidate argmin ----
// Frag-linear LDS: fragment for (k-step, lane) stored at base + k*1024 + lane*16
// -> every ds_read_b128 / write is a linear 1KB wave span (conflict-free).
__global__ __launch_bounds__(256) void vq_main(
    const float4* __restrict__ z4,
    const float4* __restrict__ emb4,
    const float* __restrict__ ne,
    float* __restrict__ out)
{
    __shared__ __align__(16) char uni[32768];     // zs fp32 -> es bf16-hi frags
    __shared__ __align__(16) char zh_lds[16384];  // zh frags [rt2][k8][q4][r16]*16B
    __shared__ float avg_lds[K_CODES];
    __shared__ float nzs[32];
    __shared__ float rowmin2[32][2];
    __shared__ float rowsum2[32][2];
    __shared__ u64   rowwin[32];
    __shared__ unsigned int list[1024];
    __shared__ int   listCount;
    __shared__ float redbuf[4];

    const int t    = threadIdx.x;
    const int n0   = blockIdx.x * 32;
    const int lane = t & 63;
    const int w    = t >> 6;
    const int rt   = w & 1;    // row tile (16 rows)
    const int ch   = w >> 1;   // code half (512 codes)

    #pragma unroll
    for (int i = 0; i < 4; ++i) avg_lds[i * 256 + t] = 0.f;
    if (t < 32) rowwin[t] = ~0ull;
    if (t == 0) listCount = 0;

    // ---- stage z fp32 tile into uni (row-major [32][256], coalesced) ----
    float* zs = reinterpret_cast<float*>(uni);
    #pragma unroll
    for (int i = 0; i < 8; ++i) {
        int f = i * 256 + t;
        reinterpret_cast<float4*>(zs)[f] = z4[(size_t)n0 * DIM4 + f];
    }
    __syncthreads();

    // ---- ||z||^2, numpy-pairwise-exact (validated verbatim) ----
    {
        const int j8   = lane & 7;
        const int blk  = (lane >> 3) & 1;
        const int rsub = lane >> 4;
        #pragma unroll
        for (int p = 0; p < 2; ++p) {
            int row = p * 16 + w * 4 + rsub;
            const float* x = zs + row * 256 + blk * 128;
            float v0 = x[j8];
            float s = __fmul_rn(v0, v0);
            #pragma unroll
            for (int b = 1; b < 16; ++b) {
                float v = x[j8 + 8 * b];
                s = __fadd_rn(s, __fmul_rn(v, v));
            }
            s = __fadd_rn(s, __shfl_xor(s, 1));
            s = __fadd_rn(s, __shfl_xor(s, 2));
            s = __fadd_rn(s, __shfl_xor(s, 4));
            s = __fadd_rn(s, __shfl_xor(s, 8));
            if ((lane & 15) == 0) nzs[row] = s;
        }
    }

    // ---- zh frag prep (frag-linear, from global z: L1/L2 hot) ----
    #pragma unroll
    for (int i = 0; i < 4; ++i) {
        int fl  = i * 256 + t;            // [0,1024)
        int r   = fl & 15;
        int q   = (fl >> 4) & 3;
        int k   = (fl >> 6) & 7;
        int rt2 = fl >> 9;
        int f40 = (n0 + rt2 * 16 + r) * DIM4 + k * 8 + q * 2;
        float4 za = z4[f40];
        float4 zb = z4[f40 + 1];
        ushort8 v;
        v[0] = f2bf(za.x); v[1] = f2bf(za.y); v[2] = f2bf(za.z); v[3] = f2bf(za.w);
        v[4] = f2bf(zb.x); v[5] = f2bf(zb.y); v[6] = f2bf(zb.z); v[7] = f2bf(zb.w);
        *reinterpret_cast<ushort8*>(zh_lds + fl * 16) = v;
    }
    __syncthreads();   // nzs + zh ready; zs reads done -> uni free for es

    f32x4 acc[32];
    #pragma unroll
    for (int i = 0; i < 32; ++i) acc[i] = (f32x4){0.f, 0.f, 0.f, 0.f};

    const char* Abase = zh_lds + rt * 8192;
    const char* Bbase = uni + ch * 16384;

    // ---- chunk loop: 16 iters x 64 codes (32 per half) ----
    #pragma unroll
    for (int it = 0; it < 16; ++it) {
        // stage 64 codes as bf16-hi frags, frag-linear (write = thread-linear)
        #pragma unroll
        for (int i = 0; i < 8; ++i) {
            int fl   = i * 256 + t;          // [0, 2048)
            int bc   = fl & 15;
            int q    = (fl >> 4) & 3;
            int k    = (fl >> 6) & 7;
            int ct   = (fl >> 9) & 1;
            int half = fl >> 10;
            int gcode = half * 512 + it * 32 + ct * 16 + bc;
            int f40 = gcode * DIM4 + k * 8 + q * 2;
            float4 ea = emb4[f40];
            float4 eb = emb4[f40 + 1];
            ushort8 v;
            v[0] = f2bf(ea.x); v[1] = f2bf(ea.y); v[2] = f2bf(ea.z); v[3] = f2bf(ea.w);
            v[4] = f2bf(eb.x); v[5] = f2bf(eb.y); v[6] = f2bf(eb.z); v[7] = f2bf(eb.w);
            *reinterpret_cast<ushort8*>(uni + fl * 16) = v;
        }
        __syncthreads();

        // MFMA: A read once per k, two B tiles (ct 0/1); all reads lane-linear
        #pragma unroll
        for (int k = 0; k < 8; ++k) {
            short8 A  = *reinterpret_cast<const short8*>(Abase + k * 1024 + lane * 16);
            short8 B0 = *reinterpret_cast<const short8*>(Bbase + k * 1024 + lane * 16);
            short8 B1 = *reinterpret_cast<const short8*>(Bbase + 8192 + k * 1024 + lane * 16);
            acc[it * 2]     = __builtin_amdgcn_mfma_f32_16x16x32_bf16(A, B0, acc[it * 2], 0, 0, 0);
            acc[it * 2 + 1] = __builtin_amdgcn_mfma_f32_16x16x32_bf16(A, B1, acc[it * 2 + 1], 0, 0, 0);
        }
        __syncthreads();
    }

    // C/D layout (m89-verified): col = lane&15, row = (lane>>4)*4 + reg
    const int bc    = lane & 15;
    const int lrow0 = rt * 16 + (lane >> 4) * 4;
    float nzv[4];
    #pragma unroll
    for (int r = 0; r < 4; ++r) nzv[r] = nzs[lrow0 + r];

    // acc[j] covers code ch*512 + (j>>1)*32 + (j&1)*16 + bc
    // ---- d~ = (nz + ne) - 2*dot (screening precision) ----
    #pragma unroll
    for (int j = 0; j < 32; ++j) {
        int code = ch * 512 + (j >> 1) * 32 + (j & 1) * 16 + bc;
        float nev = ne[code];
        #pragma unroll
        for (int r = 0; r < 4; ++r)
            acc[j][r] = (nzv[r] + nev) - 2.f * acc[j][r];
    }

    // ---- per-row min of d~ ----
    float mn[4] = {3.4e38f, 3.4e38f, 3.4e38f, 3.4e38f};
    #pragma unroll
    for (int j = 0; j < 32; ++j) {
        #pragma unroll
        for (int r = 0; r < 4; ++r) mn[r] = fminf(mn[r], acc[j][r]);
    }
    #pragma unroll
    for (int r = 0; r < 4; ++r) {
        mn[r] = fminf(mn[r], __shfl_xor(mn[r], 1));
        mn[r] = fminf(mn[r], __shfl_xor(mn[r], 2));
        mn[r] = fminf(mn[r], __shfl_xor(mn[r], 4));
        mn[r] = fminf(mn[r], __shfl_xor(mn[r], 8));
    }
    if ((lane & 15) == 0) {
        #pragma unroll
        for (int r = 0; r < 4; ++r) rowmin2[lrow0 + r][ch] = mn[r];
    }
    __syncthreads();
    float rmn[4];
    #pragma unroll
    for (int r = 0; r < 4; ++r)
        rmn[r] = fminf(rowmin2[lrow0 + r][0], rowmin2[lrow0 + r][1]);

    // ---- candidate screen ----
    #pragma unroll
    for (int j = 0; j < 32; ++j) {
        int code = ch * 512 + (j >> 1) * 32 + (j & 1) * 16 + bc;
        #pragma unroll
        for (int r = 0; r < 4; ++r) {
            if (acc[j][r] <= rmn[r] + SCREEN_W) {
                int idx = atomicAdd(&listCount, 1);
                if (idx < 1024) list[idx] = ((unsigned int)(lrow0 + r) << 10) | (unsigned int)code;
            }
        }
    }

    // ---- softmax numerators + row sums ----
    float sm[4] = {0.f, 0.f, 0.f, 0.f};
    #pragma unroll
    for (int j = 0; j < 32; ++j) {
        #pragma unroll
        for (int r = 0; r < 4; ++r) {
            float u = __expf((rmn[r] - acc[j][r]) * INV_T);
            acc[j][r] = u;
            sm[r] += u;
        }
    }
    #pragma unroll
    for (int r = 0; r < 4; ++r) {
        sm[r] += __shfl_xor(sm[r], 1);
        sm[r] += __shfl_xor(sm[r], 2);
        sm[r] += __shfl_xor(sm[r], 4);
        sm[r] += __shfl_xor(sm[r], 8);
    }
    if ((lane & 15) == 0) {
        #pragma unroll
        for (int r = 0; r < 4; ++r) rowsum2[lrow0 + r][ch] = sm[r];
    }
    __syncthreads();   // rowsums + candidate list complete

    float inv[4];
    #pragma unroll
    for (int r = 0; r < 4; ++r)
        inv[r] = 1.f / (rowsum2[lrow0 + r][0] + rowsum2[lrow0 + r][1]);

    // ---- per-code soft-prob partials -> avg_lds ----
    #pragma unroll
    for (int j = 0; j < 32; ++j) {
        float pit = acc[j][0] * inv[0] + acc[j][1] * inv[1]
                  + acc[j][2] * inv[2] + acc[j][3] * inv[3];
        pit += __shfl_xor(pit, 16);
        pit += __shfl_xor(pit, 32);
        if (lane < 16)
            atomicAdd(&avg_lds[ch * 512 + (j >> 1) * 32 + (j & 1) * 16 + lane], pit);
    }

    // ---- np-exact recompute for candidates (validated chain, verbatim) ----
    {
        int cnt = listCount; if (cnt > 1024) cnt = 1024;
        for (int i = t; i < cnt; i += 256) {
            unsigned int p = list[i];
            int lrow = (int)(p >> 10);
            int code = (int)(p & 1023u);
            const float4* zr = z4 + (size_t)(n0 + lrow) * DIM4;
            const float4* er = emb4 + (size_t)code * DIM4;
            float a0 = 0.f;
            for (int d4 = 0; d4 < DIM4; ++d4) {
                float4 v = zr[d4];
                float4 e = er[d4];
                a0 = __builtin_fmaf(v.x, e.x, a0);
                a0 = __builtin_fmaf(v.y, e.y, a0);
                a0 = __builtin_fmaf(v.z, e.z, a0);
                a0 = __builtin_fmaf(v.w, e.w, a0);
            }
            float S = __fadd_rn(nzs[lrow], ne[code]);
            float d = __fsub_rn(S, 2.f * a0);
            u64 key = ((u64)__float_as_uint(d) << 32) | (u64)(unsigned int)code;
            atomicMin(&rowwin[lrow], key);
        }
    }
    __syncthreads();

    // ---- outputs ----
    #pragma unroll
    for (int i = 0; i < 4; ++i) {
        int k = i * 256 + t;
        atomicAdd(&out[AVG_OFF + k], avg_lds[k] * (1.0f / (float)N_ROWS));
    }
    if (t < 32)
        out[IDX_OFF + n0 + t] = (float)(unsigned int)(rowwin[t] & 0xFFFFFFFFull);

    // quantized output (gather emb[idx]) + fused vq loss (z from global/L2)
    float lpart = 0.f;
    #pragma unroll
    for (int i = 0; i < 8; ++i) {
        int f = i * 256 + t;
        int r = f >> 6, d4 = f & 63;
        int bi = (int)(unsigned int)(rowwin[r] & 0xFFFFFFFFull);
        float4 q = emb4[(size_t)bi * DIM4 + d4];
        reinterpret_cast<float4*>(out)[(size_t)(n0 + r) * DIM4 + d4] = q;
        float4 zz = z4[(size_t)(n0 + r) * DIM4 + d4];
        float dx = q.x - zz.x, dy = q.y - zz.y, dz = q.z - zz.z, dw = q.w - zz.w;
        lpart += dx * dx + dy * dy + dz * dz + dw * dw;
    }
    #pragma unroll
    for (int off = 32; off >= 1; off >>= 1) lpart += __shfl_xor(lpart, off);
    if ((t & 63) == 0) redbuf[t >> 6] = lpart;
    __syncthreads();
    if (t == 0) {
        float tot = redbuf[0] + redbuf[1] + redbuf[2] + redbuf[3];
        atomicAdd(&out[LOSS_OFF], tot * (1.25f / (float)(N_ROWS * DIM)));
    }
}

extern "C" void kernel_launch(void* const* d_in, const int* in_sizes, int n_in,
                              void* d_out, int out_size, void* d_ws, size_t ws_size,
                              hipStream_t stream) {
    const float* z   = (const float*)d_in[0];
    const float* emb = (const float*)d_in[1];
    float* out = (float*)d_out;
    float* ne  = (float*)d_ws;   // 1024 floats of scratch

    vq_norms<<<dim3(4), dim3(256), 0, stream>>>(emb, ne);
    vq_init<<<dim3(4), dim3(256), 0, stream>>>(out);
    vq_main<<<dim3(N_ROWS / 32), dim3(256), 0, stream>>>(
        (const float4*)z, (const float4*)emb, ne, out);
}